// Round 11
// baseline (5548.805 us; speedup 1.0000x reference)
//
#include <hip/hip_runtime.h>
#include <hip/hip_bf16.h>

#define BB 256
#define CC 2048
#define HD 1024
#define TT 64
#define NCELL 128
#define NOUT 128

typedef short bf16x8 __attribute__((ext_vector_type(8)));
typedef float f32x4 __attribute__((ext_vector_type(4)));

__device__ __forceinline__ float sigmoidf_(float x){ return 1.0f/(1.0f+__expf(-x)); }
__device__ __forceinline__ float tanhf_(float x){ float e=__expf(2.0f*x); return 1.0f - 2.0f/(e+1.0f); }
__device__ __forceinline__ unsigned short bfbits(float x){
  __hip_bfloat16 b = __float2bfloat16(x);
  return *reinterpret_cast<unsigned short*>(&b);
}
__device__ __forceinline__ bf16x8 ldfrag(const __hip_bfloat16* p){
  return *reinterpret_cast<const bf16x8*>(p);
}
// RELEASE: drain stores, write back dirty L2 to coherence point (no invalidate).
__device__ __forceinline__ void release_wb(){
  asm volatile("s_waitcnt vmcnt(0)\n\tbuffer_wbl2 sc1\n\ts_waitcnt vmcnt(0)" ::: "memory");
}
#define MFMA16(a,b,c) __builtin_amdgcn_mfma_f32_16x16x32_bf16((a),(b),(c),0,0,0)

__global__ void cvt_f32_bf16(const float* __restrict__ in, __hip_bfloat16* __restrict__ out, int n){
  int i = (blockIdx.x*blockDim.x + threadIdx.x)*4;
  int stride = gridDim.x*blockDim.x*4;
  for (; i < n; i += stride){
    float4 v = *reinterpret_cast<const float4*>(in + i);
    ushort4 s;
    s.x = bfbits(v.x); s.y = bfbits(v.y); s.z = bfbits(v.z); s.w = bfbits(v.w);
    *reinterpret_cast<ushort4*>(out + i) = s;
  }
}

// Pack W_ih [3H][C] fp32 -> wihp[128 cell][32 col][2048] bf16.
// col c<24: gate=c>>3, jj=c&7 -> W row gate*HD + cell*8 + jj. cols 24..31 = 0 (pad).
__global__ void pack_ih(const float* __restrict__ W, __hip_bfloat16* __restrict__ out){
  size_t i = ((size_t)blockIdx.x*256 + threadIdx.x)*8;
  int k = (int)(i & 2047);
  int c = (int)((i >> 11) & 31);
  int cb = (int)(i >> 16);
  __hip_bfloat16* o = out + i;
  if (c < 24){
    const float* s = W + (size_t)((c>>3)*HD + cb*8 + (c&7))*CC + k;
#pragma unroll
    for (int e = 0; e < 8; e++) o[e] = __float2bfloat16(s[e]);
  } else {
#pragma unroll
    for (int e = 0; e < 8; e++) o[e] = __float2bfloat16(0.0f);
  }
}
// Pack W_hh [3H][H] fp32 -> whhp[128][32][1024] bf16 (same col mapping).
__global__ void pack_hh(const float* __restrict__ W, __hip_bfloat16* __restrict__ out){
  size_t i = ((size_t)blockIdx.x*256 + threadIdx.x)*8;
  int k = (int)(i & 1023);
  int c = (int)((i >> 10) & 31);
  int cb = (int)(i >> 15);
  __hip_bfloat16* o = out + i;
  if (c < 24){
    const float* s = W + (size_t)((c>>3)*HD + cb*8 + (c&7))*HD + k;
#pragma unroll
    for (int e = 0; e < 8; e++) o[e] = __float2bfloat16(s[e]);
  } else {
#pragma unroll
    for (int e = 0; e < 8; e++) o[e] = __float2bfloat16(0.0f);
  }
}

// Persistent GRU. 256 blocks x 1024 threads (16 waves).
// Even bid = cell-block (8 H-cols), odd bid = out-block (16 C-cols) -- class
// interleave keeps any 32-consecutive-block set's weight footprint ~2.8MB
// (< 4MB L2/XCD) under ANY block->XCD mapping. No invalidating fences, so
// weights stay L2-resident all 64 steps. Acts use UNIQUE per-step buffers
// (cold L2 lines can't be stale; values replay-deterministic).
// Wave tiling: 64 rows x 32 cols per wave (4 row-frags x 2 col-tiles),
// 4-way K-split + two-stage LDS reduce (round-2-proven pattern).
__global__ __launch_bounds__(1024, 4) void gru_persistent(
    const __hip_bfloat16* __restrict__ wihp,   // [128][32][2048]
    const __hip_bfloat16* __restrict__ whhp,   // [128][32][1024]
    const __hip_bfloat16* __restrict__ wout,   // [2048][1024]
    const __hip_bfloat16* __restrict__ noise16,// [256][1024]
    const float* __restrict__ bih, const float* __restrict__ bhh,
    const float* __restrict__ bout,
    float* __restrict__ samples,               // [B][T][C]
    float* __restrict__ hiddens,               // [B][T][H]
    __hip_bfloat16* __restrict__ cbufs,        // [T][B][C] unique per step
    __hip_bfloat16* __restrict__ hbufs,        // [T+1][B][H] unique per step
    unsigned* flagH, unsigned* flagC)
{
  __shared__ float arena[29696];   // red 18432 | ghbuf 9216 | hprev 2048 (floats)
  float* red   = arena;            // pitch 36 floats/lane (16B aligned)
  float* ghbuf = arena + 18432;
  float* hprev = arena + 27648;    // [row][jj] 256x8

  const int tid  = threadIdx.x;
  const int lane = tid & 63;
  const int wid  = tid >> 6;
  const int rl   = lane & 15;
  const int kg   = lane >> 4;
  const int rowg = wid & 3;        // 64-row group
  const int kq   = wid >> 2;       // K-quarter
  const int rbase= rowg*64;
  const int bid  = blockIdx.x;
  const int isCell = !(bid & 1);
  const int id2  = bid >> 1;

  auto waitflags = [&](unsigned* flags, unsigned gen){
    if (tid < 128){
      while (__hip_atomic_load(&flags[tid], __ATOMIC_RELAXED, __HIP_MEMORY_SCOPE_SYSTEM) < gen)
        __builtin_amdgcn_s_sleep(2);
    }
    __syncthreads();
  };
  auto signal = [&](unsigned* flags, int idx, unsigned gen){
    __syncthreads();               // all waves' stores drained before writeback
    if (tid == 0){
      release_wb();
      __hip_atomic_store(&flags[idx], gen, __ATOMIC_RELAXED, __HIP_MEMORY_SCOPE_SYSTEM);
    }
  };

  if (isCell){
    const int cellid = id2;
    const int jbase  = cellid*8;
    const int jj = rl & 7;
    const int j  = jbase + jj;
    const float bi_r = bih[j], bi_z = bih[j+HD], bi_n = bih[j+2*HD];
    const float bh_r = bhh[j], bh_z = bhh[j+HD], bh_n = bhh[j+2*HD];

    const __hip_bfloat16* wB0 = wihp + ((size_t)cellid*32 + rl     )*CC + kg*8;
    const __hip_bfloat16* wB1 = wihp + ((size_t)cellid*32 + 16 + rl)*CC + kg*8;
    const __hip_bfloat16* vB0 = whhp + ((size_t)cellid*32 + rl     )*HD + kg*8;
    const __hip_bfloat16* vB1 = whhp + ((size_t)cellid*32 + 16 + rl)*HD + kg*8;

#pragma unroll 1
    for (int t = 0; t < TT; t++){
      // ---------- gh = h_t @ Whh^T (skipped at t=0; overlaps out-phase) ----
      if (t > 0){
        waitflags(flagH, (unsigned)t);
        const __hip_bfloat16* hsrc = hbufs + (size_t)t*BB*HD;
        const int k0 = kq*256;
        const __hip_bfloat16* a0 = hsrc + (size_t)(rbase +  0 + rl)*HD + k0 + kg*8;
        const __hip_bfloat16* a1 = hsrc + (size_t)(rbase + 16 + rl)*HD + k0 + kg*8;
        const __hip_bfloat16* a2 = hsrc + (size_t)(rbase + 32 + rl)*HD + k0 + kg*8;
        const __hip_bfloat16* a3 = hsrc + (size_t)(rbase + 48 + rl)*HD + k0 + kg*8;
        f32x4 ag0={0},ag1={0},ag2={0},ag3={0},ag4={0},ag5={0},ag6={0},ag7={0};
#pragma unroll 2
        for (int ks = 0; ks < 8; ks++){
          bf16x8 b0 = ldfrag(vB0 + k0 + ks*32);
          bf16x8 b1 = ldfrag(vB1 + k0 + ks*32);
          bf16x8 f0 = ldfrag(a0 + ks*32);
          bf16x8 f1 = ldfrag(a1 + ks*32);
          bf16x8 f2 = ldfrag(a2 + ks*32);
          bf16x8 f3 = ldfrag(a3 + ks*32);
          ag0 = MFMA16(f0,b0,ag0); ag1 = MFMA16(f0,b1,ag1);
          ag2 = MFMA16(f1,b0,ag2); ag3 = MFMA16(f1,b1,ag3);
          ag4 = MFMA16(f2,b0,ag4); ag5 = MFMA16(f2,b1,ag5);
          ag6 = MFMA16(f3,b0,ag6); ag7 = MFMA16(f3,b1,ag7);
        }
        // two-stage K-quarter reduce -> kq0, then park in ghbuf
        if (kq >= 2){
          float* p = &red[(((kq-2)*4 + rowg)*64 + lane)*36];
          *(f32x4*)(p+0)=ag0; *(f32x4*)(p+4)=ag1; *(f32x4*)(p+8)=ag2; *(f32x4*)(p+12)=ag3;
          *(f32x4*)(p+16)=ag4; *(f32x4*)(p+20)=ag5; *(f32x4*)(p+24)=ag6; *(f32x4*)(p+28)=ag7;
        }
        __syncthreads();
        if (kq < 2){
          const float* p = &red[((kq*4 + rowg)*64 + lane)*36];
          ag0 += *(const f32x4*)(p+0);  ag1 += *(const f32x4*)(p+4);
          ag2 += *(const f32x4*)(p+8);  ag3 += *(const f32x4*)(p+12);
          ag4 += *(const f32x4*)(p+16); ag5 += *(const f32x4*)(p+20);
          ag6 += *(const f32x4*)(p+24); ag7 += *(const f32x4*)(p+28);
        }
        __syncthreads();
        if (kq == 1){
          float* p = &red[(rowg*64 + lane)*36];
          *(f32x4*)(p+0)=ag0; *(f32x4*)(p+4)=ag1; *(f32x4*)(p+8)=ag2; *(f32x4*)(p+12)=ag3;
          *(f32x4*)(p+16)=ag4; *(f32x4*)(p+20)=ag5; *(f32x4*)(p+24)=ag6; *(f32x4*)(p+28)=ag7;
        }
        __syncthreads();
        if (kq == 0){
          const float* p = &red[(rowg*64 + lane)*36];
          ag0 += *(const f32x4*)(p+0);  ag1 += *(const f32x4*)(p+4);
          ag2 += *(const f32x4*)(p+8);  ag3 += *(const f32x4*)(p+12);
          ag4 += *(const f32x4*)(p+16); ag5 += *(const f32x4*)(p+20);
          ag6 += *(const f32x4*)(p+24); ag7 += *(const f32x4*)(p+28);
          float* q_ = &ghbuf[(rowg*64 + lane)*36];
          *(f32x4*)(q_+0)=ag0; *(f32x4*)(q_+4)=ag1; *(f32x4*)(q_+8)=ag2; *(f32x4*)(q_+12)=ag3;
          *(f32x4*)(q_+16)=ag4; *(f32x4*)(q_+20)=ag5; *(f32x4*)(q_+24)=ag6; *(f32x4*)(q_+28)=ag7;
        }
        __syncthreads();
      }

      // ---------- gi = codes_t @ Wih^T ------------------------------------
      waitflags(flagC, (unsigned)(t+1));
      const __hip_bfloat16* cs = cbufs + (size_t)t*BB*CC;
      const int k0 = kq*512;
      const __hip_bfloat16* c0 = cs + (size_t)(rbase +  0 + rl)*CC + k0 + kg*8;
      const __hip_bfloat16* c1 = cs + (size_t)(rbase + 16 + rl)*CC + k0 + kg*8;
      const __hip_bfloat16* c2 = cs + (size_t)(rbase + 32 + rl)*CC + k0 + kg*8;
      const __hip_bfloat16* c3 = cs + (size_t)(rbase + 48 + rl)*CC + k0 + kg*8;
      f32x4 ai0={0},ai1={0},ai2={0},ai3={0},ai4={0},ai5={0},ai6={0},ai7={0};
#pragma unroll 2
      for (int ks = 0; ks < 16; ks++){
        bf16x8 b0 = ldfrag(wB0 + k0 + ks*32);
        bf16x8 b1 = ldfrag(wB1 + k0 + ks*32);
        bf16x8 f0 = ldfrag(c0 + ks*32);
        bf16x8 f1 = ldfrag(c1 + ks*32);
        bf16x8 f2 = ldfrag(c2 + ks*32);
        bf16x8 f3 = ldfrag(c3 + ks*32);
        ai0 = MFMA16(f0,b0,ai0); ai1 = MFMA16(f0,b1,ai1);
        ai2 = MFMA16(f1,b0,ai2); ai3 = MFMA16(f1,b1,ai3);
        ai4 = MFMA16(f2,b0,ai4); ai5 = MFMA16(f2,b1,ai5);
        ai6 = MFMA16(f3,b0,ai6); ai7 = MFMA16(f3,b1,ai7);
      }
      if (kq >= 2){
        float* p = &red[(((kq-2)*4 + rowg)*64 + lane)*36];
        *(f32x4*)(p+0)=ai0; *(f32x4*)(p+4)=ai1; *(f32x4*)(p+8)=ai2; *(f32x4*)(p+12)=ai3;
        *(f32x4*)(p+16)=ai4; *(f32x4*)(p+20)=ai5; *(f32x4*)(p+24)=ai6; *(f32x4*)(p+28)=ai7;
      }
      __syncthreads();
      if (kq < 2){
        const float* p = &red[((kq*4 + rowg)*64 + lane)*36];
        ai0 += *(const f32x4*)(p+0);  ai1 += *(const f32x4*)(p+4);
        ai2 += *(const f32x4*)(p+8);  ai3 += *(const f32x4*)(p+12);
        ai4 += *(const f32x4*)(p+16); ai5 += *(const f32x4*)(p+20);
        ai6 += *(const f32x4*)(p+24); ai7 += *(const f32x4*)(p+28);
      }
      __syncthreads();
      if (kq == 1){
        float* p = &red[(rowg*64 + lane)*36];
        *(f32x4*)(p+0)=ai0; *(f32x4*)(p+4)=ai1; *(f32x4*)(p+8)=ai2; *(f32x4*)(p+12)=ai3;
        *(f32x4*)(p+16)=ai4; *(f32x4*)(p+20)=ai5; *(f32x4*)(p+24)=ai6; *(f32x4*)(p+28)=ai7;
      }
      __syncthreads();
      if (kq == 0){
        const float* p = &red[(rowg*64 + lane)*36];
        ai0 += *(const f32x4*)(p+0);  ai1 += *(const f32x4*)(p+4);
        ai2 += *(const f32x4*)(p+8);  ai3 += *(const f32x4*)(p+12);
        ai4 += *(const f32x4*)(p+16); ai5 += *(const f32x4*)(p+20);
        ai6 += *(const f32x4*)(p+24); ai7 += *(const f32x4*)(p+28);

        // epilogue: cols [0..7]=r, [8..15]=z (shfl), tile1 [0..7]=n
        __hip_bfloat16* hn = hbufs + (size_t)(t+1)*BB*HD;
        const float* gb = &ghbuf[(rowg*64)*36];
        const int plR = (lane & 48) | jj;
        const int plZ = plR | 8;
#pragma unroll
        for (int rf = 0; rf < 4; rf++){
          f32x4 air = (rf==0)?ai0:(rf==1)?ai2:(rf==2)?ai4:ai6;
          f32x4 ain = (rf==0)?ai1:(rf==1)?ai3:(rf==2)?ai5:ai7;
#pragma unroll
          for (int q = 0; q < 4; q++){
            float zi = __shfl_xor(air[q], 8, 64);
            if (rl < 8){
              const int row = rbase + rf*16 + kg*4 + q;
              float gr = 0.f, gz = 0.f, gn = 0.f;
              if (t > 0){
                gr = gb[plR*36 + (rf*2+0)*4 + q];
                gz = gb[plZ*36 + (rf*2+0)*4 + q];
                gn = gb[plR*36 + (rf*2+1)*4 + q];
              }
              float r = sigmoidf_(air[q] + gr + bi_r + bh_r);
              float z = sigmoidf_(zi + gz + bi_z + bh_z);
              float n = tanhf_(ain[q] + bi_n + r*(gn + bh_n));
              float hp = (t == 0) ? 0.f : hprev[row*8 + jj];
              float hv = (1.f - z)*n + z*hp;
              hprev[row*8 + jj] = hv;
              __builtin_nontemporal_store(hv, &hiddens[(size_t)row*TT*HD + (size_t)t*HD + j]);
              hn[(size_t)row*HD + j] = __float2bfloat16(hv);
            }
          }
        }
      }
      signal(flagH, cellid, (unsigned)(t+1));
    }
  } else {
    // ------------------------------ OUT -----------------------------------
    const int outid = id2;
    const int col = outid*16 + rl;
    const float bo = bout[col];
    const __hip_bfloat16* wB = wout + (size_t)col*HD + kg*8;

#pragma unroll 1
    for (int t = 0; t < TT; t++){
      const __hip_bfloat16* hsrc;
      if (t == 0){
        hsrc = noise16;
      } else {
        waitflags(flagH, (unsigned)t);
        hsrc = hbufs + (size_t)t*BB*HD;
      }
      const int k0 = kq*256;
      const __hip_bfloat16* a0 = hsrc + (size_t)(rbase +  0 + rl)*HD + k0 + kg*8;
      const __hip_bfloat16* a1 = hsrc + (size_t)(rbase + 16 + rl)*HD + k0 + kg*8;
      const __hip_bfloat16* a2 = hsrc + (size_t)(rbase + 32 + rl)*HD + k0 + kg*8;
      const __hip_bfloat16* a3 = hsrc + (size_t)(rbase + 48 + rl)*HD + k0 + kg*8;
      f32x4 ac0={0},ac1={0},ac2={0},ac3={0};
#pragma unroll 2
      for (int ks = 0; ks < 8; ks++){
        bf16x8 b = ldfrag(wB + k0 + ks*32);
        ac0 = MFMA16(ldfrag(a0 + ks*32), b, ac0);
        ac1 = MFMA16(ldfrag(a1 + ks*32), b, ac1);
        ac2 = MFMA16(ldfrag(a2 + ks*32), b, ac2);
        ac3 = MFMA16(ldfrag(a3 + ks*32), b, ac3);
      }
      if (kq >= 2){
        float* p = &red[(((kq-2)*4 + rowg)*64 + lane)*20];
        *(f32x4*)(p+0)=ac0; *(f32x4*)(p+4)=ac1; *(f32x4*)(p+8)=ac2; *(f32x4*)(p+12)=ac3;
      }
      __syncthreads();
      if (kq < 2){
        const float* p = &red[((kq*4 + rowg)*64 + lane)*20];
        ac0 += *(const f32x4*)(p+0); ac1 += *(const f32x4*)(p+4);
        ac2 += *(const f32x4*)(p+8); ac3 += *(const f32x4*)(p+12);
      }
      __syncthreads();
      if (kq == 1){
        float* p = &red[(rowg*64 + lane)*20];
        *(f32x4*)(p+0)=ac0; *(f32x4*)(p+4)=ac1; *(f32x4*)(p+8)=ac2; *(f32x4*)(p+12)=ac3;
      }
      __syncthreads();
      if (kq == 0){
        const float* p = &red[(rowg*64 + lane)*20];
        ac0 += *(const f32x4*)(p+0); ac1 += *(const f32x4*)(p+4);
        ac2 += *(const f32x4*)(p+8); ac3 += *(const f32x4*)(p+12);
        __hip_bfloat16* cd = cbufs + (size_t)t*BB*CC;
#pragma unroll
        for (int rf = 0; rf < 4; rf++){
          f32x4 a = (rf==0)?ac0:(rf==1)?ac1:(rf==2)?ac2:ac3;
#pragma unroll
          for (int q = 0; q < 4; q++){
            const int row = rbase + rf*16 + kg*4 + q;
            float sv = sigmoidf_(a[q] + bo);
            __builtin_nontemporal_store(sv, &samples[(size_t)row*TT*CC + (size_t)t*CC + col]);
            cd[(size_t)row*CC + col] = __float2bfloat16(sv);
          }
        }
      }
      signal(flagC, outid, (unsigned)(t+1));
    }
  }
}

extern "C" void kernel_launch(void* const* d_in, const int* in_sizes, int n_in,
                              void* d_out, int out_size, void* d_ws, size_t ws_size,
                              hipStream_t stream) {
  const float* noise = (const float*)d_in[0];
  const float* W_ih  = (const float*)d_in[1];
  const float* b_ih  = (const float*)d_in[2];
  const float* W_hh  = (const float*)d_in[3];
  const float* b_hh  = (const float*)d_in[4];
  const float* W_out = (const float*)d_in[5];
  const float* b_out = (const float*)d_in[6];

  float* samples = (float*)d_out;                  // [B][T][C]
  float* hiddens = samples + (size_t)BB*TT*CC;     // [B][T][H]

  char* w = (char*)d_ws;
  unsigned* flagH = (unsigned*)w;              w += 2048;
  unsigned* flagC = (unsigned*)w;              w += 2048;
  __hip_bfloat16* wihp  = (__hip_bfloat16*)w;  w += (size_t)NCELL*32*CC*2;   // 16.8MB
  __hip_bfloat16* whhp  = (__hip_bfloat16*)w;  w += (size_t)NCELL*32*HD*2;   // 8.4MB
  __hip_bfloat16* wout16= (__hip_bfloat16*)w;  w += (size_t)CC*HD*2;         // 4.2MB
  __hip_bfloat16* noise16=(__hip_bfloat16*)w;  w += (size_t)BB*HD*2;
  __hip_bfloat16* cbufs = (__hip_bfloat16*)w;  w += (size_t)TT*BB*CC*2;      // 67MB
  __hip_bfloat16* hbufs = (__hip_bfloat16*)w;  w += (size_t)(TT+1)*BB*HD*2;  // 34MB

  hipMemsetAsync(flagH, 0, 4096, stream);
  pack_ih<<<4096, 256, 0, stream>>>(W_ih, wihp);
  pack_hh<<<2048, 256, 0, stream>>>(W_hh, whhp);
  cvt_f32_bf16<<<1024, 256, 0, stream>>>(W_out, wout16, CC*HD);
  cvt_f32_bf16<<<256,  256, 0, stream>>>(noise, noise16, BB*HD);

  gru_persistent<<<256, 1024, 0, stream>>>(
      wihp, whhp, wout16, noise16, b_ih, b_hh, b_out,
      samples, hiddens, cbufs, hbufs, flagH, flagC);
}

// Round 12
// 4158.284 us; speedup vs baseline: 1.3344x; 1.3344x over previous
//
#include <hip/hip_runtime.h>
#include <hip/hip_bf16.h>

#define BB 256
#define CC 2048
#define HD 1024
#define TT 64

typedef short bf16x8 __attribute__((ext_vector_type(8)));
typedef float f32x4 __attribute__((ext_vector_type(4)));
typedef int   i32x4 __attribute__((ext_vector_type(4)));

__device__ __forceinline__ float sigmoidf_(float x){ return 1.0f/(1.0f+__expf(-x)); }
__device__ __forceinline__ float tanhf_(float x){ float e=__expf(2.0f*x); return 1.0f - 2.0f/(e+1.0f); }
__device__ __forceinline__ unsigned short bfbits(float x){
  __hip_bfloat16 b = __float2bfloat16(x);
  return *reinterpret_cast<unsigned short*>(&b);
}
__device__ __forceinline__ bf16x8 ldfrag(const __hip_bfloat16* p){
  return *reinterpret_cast<const bf16x8*>(p);
}
// RELEASE: drain stores, write back dirty L2 to the coherence point (no invalidate).
__device__ __forceinline__ void release_wb(){
  asm volatile("s_waitcnt vmcnt(0)\n\tbuffer_wbl2 sc1\n\ts_waitcnt vmcnt(0)" ::: "memory");
}
#define MFMA16(a,b,c) __builtin_amdgcn_mfma_f32_16x16x32_bf16((a),(b),(c),0,0,0)

__global__ void cvt_f32_bf16(const float* __restrict__ in, __hip_bfloat16* __restrict__ out, int n){
  int i = (blockIdx.x*blockDim.x + threadIdx.x)*4;
  int stride = gridDim.x*blockDim.x*4;
  for (; i < n; i += stride){
    float4 v = *reinterpret_cast<const float4*>(in + i);
    ushort4 s;
    s.x = bfbits(v.x); s.y = bfbits(v.y); s.z = bfbits(v.z); s.w = bfbits(v.w);
    *reinterpret_cast<ushort4*>(out + i) = s;
  }
}

// W_ih [3H][C] f32 -> wihp[256 blk][16 slot][2048] bf16.
// slot s<12: gate=s>>2, col=blk*4+(s&3) -> row gate*HD+col. slots 12-15 zero.
__global__ void pack_ih(const float* __restrict__ W, __hip_bfloat16* __restrict__ out){
  size_t i = ((size_t)blockIdx.x*256 + threadIdx.x)*8;
  int k = (int)(i & 2047), r = (int)((i>>11) & 15), b = (int)(i>>15);
  __hip_bfloat16* o = out + i;
  if (r < 12){
    const float* s = W + (size_t)((r>>2)*HD + b*4 + (r&3))*CC + k;
#pragma unroll
    for (int e = 0; e < 8; e++) o[e] = __float2bfloat16(s[e]);
  } else {
#pragma unroll
    for (int e = 0; e < 8; e++) o[e] = __float2bfloat16(0.0f);
  }
}
// W_hh [3H][H] -> whhp[256][16][1024] (same slot map, K=1024).
__global__ void pack_hh(const float* __restrict__ W, __hip_bfloat16* __restrict__ out){
  size_t i = ((size_t)blockIdx.x*256 + threadIdx.x)*8;
  int k = (int)(i & 1023), r = (int)((i>>10) & 15), b = (int)(i>>14);
  __hip_bfloat16* o = out + i;
  if (r < 12){
    const float* s = W + (size_t)((r>>2)*HD + b*4 + (r&3))*HD + k;
#pragma unroll
    for (int e = 0; e < 8; e++) o[e] = __float2bfloat16(s[e]);
  } else {
#pragma unroll
    for (int e = 0; e < 8; e++) o[e] = __float2bfloat16(0.0f);
  }
}
// W_out [C][H] -> woutp[256][16][1024]. slot s<8: C-col blk*8+s. 8-15 zero.
__global__ void pack_out(const float* __restrict__ W, __hip_bfloat16* __restrict__ out){
  size_t i = ((size_t)blockIdx.x*256 + threadIdx.x)*8;
  int k = (int)(i & 1023), r = (int)((i>>10) & 15), b = (int)(i>>14);
  __hip_bfloat16* o = out + i;
  if (r < 8){
    const float* s = W + (size_t)(b*8 + r)*HD + k;
#pragma unroll
    for (int e = 0; e < 8; e++) o[e] = __float2bfloat16(s[e]);
  } else {
#pragma unroll
    for (int e = 0; e < 8; e++) o[e] = __float2bfloat16(0.0f);
  }
}

#define IH_PITCH 4112   // 2048*2 + 16 pad
#define HO_PITCH 2064   // 1024*2 + 16 pad

// Persistent GRU, 256 blocks x 1024 threads (16 waves), 1 block/CU.
// ALL WEIGHTS LIVE IN LDS (129KB/block, zero weight traffic after startup).
// Block b owns H-cols [b*4,+4) (12 gate slots of Wih/Whh) and C-cols [b*8,+8)
// of Wout. Full-M: every wave computes 16 batch rows x full K (no reduction).
// Per step: phase1 = fused {logits + gh} from h_t (one h read), signal C;
// phase2 = gi from codes_t, in-lane gate combine (h_prev in registers), signal H.
// Activations use unique-per-step global buffers -> normal cached loads are
// safe (first touch post-wbl2; replay-stale lines hold identical values).
__global__ __launch_bounds__(1024, 4) void gru_persistent(
    const __hip_bfloat16* __restrict__ wihp,   // [256][16][2048]
    const __hip_bfloat16* __restrict__ whhp,   // [256][16][1024]
    const __hip_bfloat16* __restrict__ woutp,  // [256][16][1024]
    const __hip_bfloat16* __restrict__ noise16,// [256][1024]
    const float* __restrict__ bih, const float* __restrict__ bhh,
    const float* __restrict__ bout,
    float* __restrict__ samples,               // [B][T][C]
    float* __restrict__ hiddens,               // [B][T][H]
    __hip_bfloat16* __restrict__ cbufs,        // [T][B][C]
    __hip_bfloat16* __restrict__ hbufs,        // [T+1][B][H]
    unsigned* flagC, unsigned* flagH)
{
  __shared__ __align__(16) char lds[16*IH_PITCH + 32*HO_PITCH];  // 131840B
  char* ldsIh  = lds;
  char* ldsHh  = lds + 16*IH_PITCH;
  char* ldsOut = lds + 16*IH_PITCH + 16*HO_PITCH;

  const int tid  = threadIdx.x;
  const int lane = tid & 63;
  const int wid  = tid >> 6;      // 0..15 -> M-tile
  const int b    = blockIdx.x;
  const int rl   = lane & 15;
  const int kg   = lane >> 4;
  const int m0   = wid*16;
  const int j0   = b*4;           // owned H-cols
  const int c0   = b*8;           // owned C-cols

  // ---- weights global -> LDS (once) ----
  for (int c = tid; c < 4096; c += 1024){
    int row = c >> 8, kB = (c & 255) << 4;
    *(i32x4*)(ldsIh + row*IH_PITCH + kB) =
      *(const i32x4*)((const char*)wihp + (size_t)b*65536 + row*4096 + kB);
  }
  for (int c = tid; c < 2048; c += 1024){
    int row = c >> 7, kB = (c & 127) << 4;
    *(i32x4*)(ldsHh + row*HO_PITCH + kB) =
      *(const i32x4*)((const char*)whhp + (size_t)b*32768 + row*2048 + kB);
  }
  for (int c = tid; c < 2048; c += 1024){
    int row = c >> 7, kB = (c & 127) << 4;
    *(i32x4*)(ldsOut + row*HO_PITCH + kB) =
      *(const i32x4*)((const char*)woutp + (size_t)b*32768 + row*2048 + kB);
  }
  __syncthreads();

  // per-lane LDS B-frag bases (B-frag: col = rl, k-elems kg*8 of 32-window)
  const char* pIh  = ldsIh  + rl*IH_PITCH + kg*16;
  const char* pHh  = ldsHh  + rl*HO_PITCH + kg*16;
  const char* pOut = ldsOut + rl*HO_PITCH + kg*16;

  // biases (lane-resident)
  const int gsel = (rl < 12) ? (rl >> 2) : 0;
  const int jcol = j0 + (rl & 3);
  const float bi_g = bih[gsel*HD + jcol];
  const float bh_g = bhh[gsel*HD + jcol];
  const float bo   = bout[c0 + (rl & 7)];

  float hp[4] = {0.f, 0.f, 0.f, 0.f};   // h_t[m0+kg*4+q][j0+rl], lanes rl<4

  auto waitflags = [&](unsigned* flags, unsigned gen){
    if (tid < 256){
      while (__hip_atomic_load(&flags[tid], __ATOMIC_RELAXED, __HIP_MEMORY_SCOPE_SYSTEM) < gen)
        __builtin_amdgcn_s_sleep(2);
    }
    __syncthreads();
  };
  auto signal = [&](unsigned* flags, unsigned gen){
    __syncthreads();               // drain all waves' stores (vmcnt0 before barrier)
    if (tid == 0){
      release_wb();
      __hip_atomic_store(&flags[b], gen, __ATOMIC_RELAXED, __HIP_MEMORY_SCOPE_SYSTEM);
    }
  };

#pragma unroll 1
  for (int t = 0; t < TT; t++){
    // -------- phase 1: fused logits + gh from h_t (noise at t=0) ----------
    if (t > 0) waitflags(flagH, (unsigned)t);
    const __hip_bfloat16* hsrc = (t == 0) ? noise16 : (hbufs + (size_t)t*BB*HD);
    const __hip_bfloat16* arow = hsrc + (size_t)(m0 + rl)*HD + kg*8;
    f32x4 accL = {0.f,0.f,0.f,0.f}, accG = {0.f,0.f,0.f,0.f};
#pragma unroll 4
    for (int k = 0; k < HD; k += 32){
      bf16x8 a = ldfrag(arow + k);
      accL = MFMA16(a, *(const bf16x8*)(pOut + k*2), accL);
      accG = MFMA16(a, *(const bf16x8*)(pHh  + k*2), accG);
    }
    if (t == 0) accG = (f32x4){0.f,0.f,0.f,0.f};   // h0 = 0 -> gh = 0

    __hip_bfloat16* cd = cbufs + (size_t)t*BB*CC;
    if (rl < 8){
#pragma unroll
      for (int q = 0; q < 4; q++){
        const int row = m0 + kg*4 + q;
        float sv = sigmoidf_(accL[q] + bo);
        __builtin_nontemporal_store(sv, &samples[(size_t)row*TT*CC + (size_t)t*CC + c0 + rl]);
        cd[(size_t)row*CC + c0 + rl] = __float2bfloat16(sv);
      }
    }
    signal(flagC, (unsigned)(t+1));

    // -------- phase 2: gi from codes_t + gate combine ---------------------
    waitflags(flagC, (unsigned)(t+1));
    const __hip_bfloat16* crow = cbufs + (size_t)t*BB*CC + (size_t)(m0 + rl)*CC + kg*8;
    f32x4 accI = {0.f,0.f,0.f,0.f};
#pragma unroll 8
    for (int k = 0; k < CC; k += 32){
      accI = MFMA16(ldfrag(crow + k), *(const bf16x8*)(pIh + k*2), accI);
    }

    __hip_bfloat16* hn = hbufs + (size_t)(t+1)*BB*HD;
    const int base = lane & 48;
    const int jj   = rl & 3;
#pragma unroll
    for (int q = 0; q < 4; q++){
      float sI = accI[q] + bi_g;         // gi + b_ih (this lane's gate/col)
      float sH = accG[q] + bh_g;         // gh + b_hh
      float sAll = sI + sH;
      float rs  = __shfl(sAll, base + jj,     64);
      float zs  = __shfl(sAll, base + 4 + jj, 64);
      float giN = __shfl(sI,   base + 8 + jj, 64);
      float ghN = __shfl(sH,   base + 8 + jj, 64);
      if (rl < 4){
        float rv = sigmoidf_(rs);
        float zv = sigmoidf_(zs);
        float nv = tanhf_(giN + rv*ghN);
        float hv = (1.0f - zv)*nv + zv*hp[q];
        hp[q] = hv;
        const int row = m0 + kg*4 + q;
        __builtin_nontemporal_store(hv, &hiddens[(size_t)row*TT*HD + (size_t)t*HD + j0 + rl]);
        hn[(size_t)row*HD + j0 + rl] = __float2bfloat16(hv);
      }
    }
    signal(flagH, (unsigned)(t+1));
  }
}

extern "C" void kernel_launch(void* const* d_in, const int* in_sizes, int n_in,
                              void* d_out, int out_size, void* d_ws, size_t ws_size,
                              hipStream_t stream) {
  const float* noise = (const float*)d_in[0];
  const float* W_ih  = (const float*)d_in[1];
  const float* b_ih  = (const float*)d_in[2];
  const float* W_hh  = (const float*)d_in[3];
  const float* b_hh  = (const float*)d_in[4];
  const float* W_out = (const float*)d_in[5];
  const float* b_out = (const float*)d_in[6];

  float* samples = (float*)d_out;                  // [B][T][C]
  float* hiddens = samples + (size_t)BB*TT*CC;     // [B][T][H]

  char* w = (char*)d_ws;
  unsigned* flagC = (unsigned*)w;              w += 1024;
  unsigned* flagH = (unsigned*)w;              w += 1024;
  __hip_bfloat16* wihp  = (__hip_bfloat16*)w;  w += (size_t)256*16*CC*2;     // 16MB
  __hip_bfloat16* whhp  = (__hip_bfloat16*)w;  w += (size_t)256*16*HD*2;     // 8MB
  __hip_bfloat16* woutp = (__hip_bfloat16*)w;  w += (size_t)256*16*HD*2;     // 8MB
  __hip_bfloat16* noise16=(__hip_bfloat16*)w;  w += (size_t)BB*HD*2;
  __hip_bfloat16* cbufs = (__hip_bfloat16*)w;  w += (size_t)TT*BB*CC*2;      // 64MB
  __hip_bfloat16* hbufs = (__hip_bfloat16*)w;  w += (size_t)(TT+1)*BB*HD*2;  // 34MB

  hipMemsetAsync(flagC, 0, 2048, stream);
  pack_ih <<<4096, 256, 0, stream>>>(W_ih,  wihp);
  pack_hh <<<2048, 256, 0, stream>>>(W_hh,  whhp);
  pack_out<<<2048, 256, 0, stream>>>(W_out, woutp);
  cvt_f32_bf16<<<256, 256, 0, stream>>>(noise, noise16, BB*HD);

  gru_persistent<<<256, 1024, 0, stream>>>(
      wihp, whhp, woutp, noise16, b_ih, b_hh, b_out,
      samples, hiddens, cbufs, hbufs, flagC, flagH);
}